// Round 1
// baseline (629.011 us; speedup 1.0000x reference)
//
#include <hip/hip_runtime.h>

// Problem dims
#define MB_T 16384   // B*T
#define DD   512     // model hidden
#define CC   4096    // context entries
#define AA   512     // attn dim
#define PP   512     // out dim

typedef __attribute__((ext_vector_type(4))) float f32x4;
typedef __attribute__((ext_vector_type(8))) short short8;

#define MFMA16(a, b, c) __builtin_amdgcn_mfma_f32_16x16x32_bf16((a), (b), (c), 0, 0, 0)

__device__ __forceinline__ unsigned short f2bf(float f) {
  union { float f; unsigned int u; } cv; cv.f = f;
  unsigned int u = cv.u;
  return (unsigned short)((u + 0x7FFFu + ((u >> 16) & 1u)) >> 16);
}

// ---------------- cast fp32 -> bf16, x4 vectorized ----------------
__global__ void cast_bf16_kernel(const float* __restrict__ in,
                                 unsigned short* __restrict__ out, int n4) {
  int i = blockIdx.x * blockDim.x + threadIdx.x;
  int stride = gridDim.x * blockDim.x;
  for (; i < n4; i += stride) {
    float4 v = reinterpret_cast<const float4*>(in)[i];
    ushort4 o;
    o.x = f2bf(v.x); o.y = f2bf(v.y); o.z = f2bf(v.z); o.w = f2bf(v.w);
    reinterpret_cast<ushort4*>(out)[i] = o;
  }
}

// ---------------- W [rows][cols] f32 -> WT [cols][rows] bf16 ----------------
__global__ __launch_bounds__(256) void transpose_cast_kernel(
    const float* __restrict__ W, unsigned short* __restrict__ WT, int rows, int cols) {
  __shared__ float t_s[32][33];
  int bi = blockIdx.y * 32, bj = blockIdx.x * 32;
  int r = threadIdx.x >> 3, c4 = (threadIdx.x & 7) * 4;
  float4 v = *reinterpret_cast<const float4*>(W + (size_t)(bi + r) * cols + bj + c4);
  t_s[r][c4 + 0] = v.x; t_s[r][c4 + 1] = v.y;
  t_s[r][c4 + 2] = v.z; t_s[r][c4 + 3] = v.w;
  __syncthreads();
  ushort4 o;
  o.x = f2bf(t_s[c4 + 0][r]);
  o.y = f2bf(t_s[c4 + 1][r]);
  o.z = f2bf(t_s[c4 + 2][r]);
  o.w = f2bf(t_s[c4 + 3][r]);
  *reinterpret_cast<ushort4*>(WT + (size_t)(bj + r) * rows + bi + c4) = o;
}

// ---------------- generic GEMM: C = (A @ BT^T + bias) * alpha ----------------
// A [M][K] bf16 row-major, BT [N][K] bf16 row-major.
// MODE 0: C bf16 [M][N];  MODE 1: C bf16 transposed [N][M];  MODE 2: C f32 [M][N]
template <int MODE>
__global__ __launch_bounds__(256) void gemm_bt_kernel(
    const unsigned short* __restrict__ Abf, const unsigned short* __restrict__ BTbf,
    const float* __restrict__ bias, void* __restrict__ Cout,
    int M, int N, int K, float alpha) {
  __shared__ unsigned short a_s[128][40];  // 40: pad -> 16B aligned rows, 2-way banks
  __shared__ unsigned short b_s[128][40];
  const int tid = threadIdx.x;
  const int lane = tid & 63;
  const int wid = tid >> 6;
  const int hq = lane >> 4, lq = lane & 15;
  const int wm = wid >> 1, wn = wid & 1;
  const int brow = blockIdx.y * 128, bcol = blockIdx.x * 128;
  const int r0 = tid >> 2, seg = tid & 3;
  f32x4 acc[4][4] = {};
  for (int k0 = 0; k0 < K; k0 += 32) {
#pragma unroll
    for (int it = 0; it < 2; ++it) {
      int r = r0 + it * 64;
      *reinterpret_cast<int4*>(&a_s[r][seg * 8]) =
          *reinterpret_cast<const int4*>(Abf + (size_t)(brow + r) * K + k0 + seg * 8);
      *reinterpret_cast<int4*>(&b_s[r][seg * 8]) =
          *reinterpret_cast<const int4*>(BTbf + (size_t)(bcol + r) * K + k0 + seg * 8);
    }
    __syncthreads();
    short8 af[4], bfr[4];
#pragma unroll
    for (int mf = 0; mf < 4; ++mf)
      af[mf] = *reinterpret_cast<const short8*>(&a_s[wm * 64 + mf * 16 + lq][hq * 8]);
#pragma unroll
    for (int nf = 0; nf < 4; ++nf)
      bfr[nf] = *reinterpret_cast<const short8*>(&b_s[wn * 64 + nf * 16 + lq][hq * 8]);
#pragma unroll
    for (int mf = 0; mf < 4; ++mf)
#pragma unroll
      for (int nf = 0; nf < 4; ++nf)
        acc[mf][nf] = MFMA16(af[mf], bfr[nf], acc[mf][nf]);
    __syncthreads();
  }
#pragma unroll
  for (int nf = 0; nf < 4; ++nf) {
    int colg = bcol + wn * 64 + nf * 16 + lq;
    float bv = bias[colg];
#pragma unroll
    for (int mf = 0; mf < 4; ++mf) {
      int rowg0 = brow + wm * 64 + mf * 16 + hq * 4;
      if (MODE == 1) {
        ushort4 pk;
        pk.x = f2bf((acc[mf][nf][0] + bv) * alpha);
        pk.y = f2bf((acc[mf][nf][1] + bv) * alpha);
        pk.z = f2bf((acc[mf][nf][2] + bv) * alpha);
        pk.w = f2bf((acc[mf][nf][3] + bv) * alpha);
        *reinterpret_cast<ushort4*>((unsigned short*)Cout + (size_t)colg * M + rowg0) = pk;
      } else {
#pragma unroll
        for (int i = 0; i < 4; ++i) {
          float v = (acc[mf][nf][i] + bv) * alpha;
          if (MODE == 0)
            ((unsigned short*)Cout)[(size_t)(rowg0 + i) * N + colg] = f2bf(v);
          else
            ((float*)Cout)[(size_t)(rowg0 + i) * N + colg] = v;
        }
      }
    }
  }
}

// ---------------- flash attention (no-max softmax; scale pre-folded into q) ----------------
// q [16384][512] bf16 (pre-scaled), k [4096][512] bf16, vT [512][4096] bf16 -> x [16384][512] bf16
__global__ __launch_bounds__(512) void flash_kernel(
    const unsigned short* __restrict__ qb, const unsigned short* __restrict__ kb,
    const unsigned short* __restrict__ vtb, unsigned short* __restrict__ xb) {
  __shared__ unsigned short q_s[32][520];   // padded: 1040B rows, 16B aligned
  __shared__ unsigned short p_s[32][264];   // padded: 528B rows
  __shared__ float l_part[8][32];
  const int tid = threadIdx.x;
  const int lane = tid & 63, wid = tid >> 6;
  const int hq = lane >> 4, lq = lane & 15;
  const int brow = blockIdx.x * 32;

  {
    int chunk = tid;
#pragma unroll
    for (int it = 0; it < 4; ++it, chunk += 512) {
      int r = chunk >> 6, c8 = chunk & 63;
      *reinterpret_cast<int4*>(&q_s[r][c8 * 8]) =
          *reinterpret_cast<const int4*>(qb + (size_t)(brow + r) * 512 + c8 * 8);
    }
  }
  __syncthreads();

  f32x4 acc[2][4] = {};
  float lsums[8] = {0.f, 0.f, 0.f, 0.f, 0.f, 0.f, 0.f, 0.f};

  for (int ct = 0; ct < 16; ++ct) {
    const int c0 = ct * 256;
    const int cbase = c0 + wid * 32;
    f32x4 sm[2][2] = {};
#pragma unroll
    for (int ks = 0; ks < 16; ++ks) {
      short8 a0 = *reinterpret_cast<const short8*>(&q_s[lq][ks * 32 + hq * 8]);
      short8 a1 = *reinterpret_cast<const short8*>(&q_s[16 + lq][ks * 32 + hq * 8]);
      short8 b0 = *reinterpret_cast<const short8*>(kb + (size_t)(cbase + lq) * 512 + ks * 32 + hq * 8);
      short8 b1 = *reinterpret_cast<const short8*>(kb + (size_t)(cbase + 16 + lq) * 512 + ks * 32 + hq * 8);
      sm[0][0] = MFMA16(a0, b0, sm[0][0]);
      sm[0][1] = MFMA16(a0, b1, sm[0][1]);
      sm[1][0] = MFMA16(a1, b0, sm[1][0]);
      sm[1][1] = MFMA16(a1, b1, sm[1][1]);
    }
    // exp, accumulate row-sums, write P tile to LDS (bf16)
#pragma unroll
    for (int mf = 0; mf < 2; ++mf)
#pragma unroll
      for (int nf = 0; nf < 2; ++nf)
#pragma unroll
        for (int i = 0; i < 4; ++i) {
          float p = __expf(sm[mf][nf][i]);
          lsums[mf * 4 + i] += p;
          p_s[mf * 16 + hq * 4 + i][wid * 32 + nf * 16 + lq] = f2bf(p);
        }
    __syncthreads();
    const int abase = wid * 64;
#pragma unroll
    for (int ks2 = 0; ks2 < 8; ++ks2) {
      short8 pa0 = *reinterpret_cast<const short8*>(&p_s[lq][ks2 * 32 + hq * 8]);
      short8 pa1 = *reinterpret_cast<const short8*>(&p_s[16 + lq][ks2 * 32 + hq * 8]);
#pragma unroll
      for (int nf = 0; nf < 4; ++nf) {
        short8 vb = *reinterpret_cast<const short8*>(
            vtb + (size_t)(abase + nf * 16 + lq) * 4096 + c0 + ks2 * 32 + hq * 8);
        acc[0][nf] = MFMA16(pa0, vb, acc[0][nf]);
        acc[1][nf] = MFMA16(pa1, vb, acc[1][nf]);
      }
    }
    __syncthreads();
  }

  // reduce lsums across the 16 lanes of each hq group (cols) -> full row sums per wave
#pragma unroll
  for (int s = 0; s < 8; ++s) {
    float v = lsums[s];
    v += __shfl_xor(v, 1);
    v += __shfl_xor(v, 2);
    v += __shfl_xor(v, 4);
    v += __shfl_xor(v, 8);
    lsums[s] = v;
  }
  if (lq == 0) {
#pragma unroll
    for (int mf = 0; mf < 2; ++mf)
#pragma unroll
      for (int i = 0; i < 4; ++i)
        l_part[wid][mf * 16 + hq * 4 + i] = lsums[mf * 4 + i];
  }
  __syncthreads();

#pragma unroll
  for (int mf = 0; mf < 2; ++mf)
#pragma unroll
    for (int i = 0; i < 4; ++i) {
      int row = mf * 16 + hq * 4 + i;
      float tot = 0.f;
#pragma unroll
      for (int w = 0; w < 8; ++w) tot += l_part[w][row];
      float inv = 1.0f / tot;
#pragma unroll
      for (int nf = 0; nf < 4; ++nf)
        xb[(size_t)(brow + row) * 512 + wid * 64 + nf * 16 + lq] =
            f2bf(acc[mf][nf][i] * inv);
    }
}

extern "C" void kernel_launch(void* const* d_in, const int* in_sizes, int n_in,
                              void* d_out, int out_size, void* d_ws, size_t ws_size,
                              hipStream_t stream) {
  const float* model = (const float*)d_in[0];
  const float* ctx   = (const float*)d_in[1];
  const float* Wq = (const float*)d_in[2]; const float* bq = (const float*)d_in[3];
  const float* Wk = (const float*)d_in[4]; const float* bk = (const float*)d_in[5];
  const float* Wv = (const float*)d_in[6]; const float* bv = (const float*)d_in[7];
  const float* Wo = (const float*)d_in[8]; const float* bo = (const float*)d_in[9];
  float* out = (float*)d_out;

  char* ws = (char*)d_ws;
  size_t off = 0;
  auto alloc = [&](size_t bytes) -> void* {
    void* p = ws + off;
    off += (bytes + 255) & ~(size_t)255;
    return p;
  };
  unsigned short* model_bf = (unsigned short*)alloc((size_t)MB_T * DD * 2);
  unsigned short* ctx_bf   = (unsigned short*)alloc((size_t)CC * DD * 2);
  unsigned short* q_bf     = (unsigned short*)alloc((size_t)MB_T * AA * 2);
  unsigned short* k_bf     = (unsigned short*)alloc((size_t)CC * AA * 2);
  unsigned short* vT_bf    = (unsigned short*)alloc((size_t)AA * CC * 2);
  unsigned short* WqT = (unsigned short*)alloc((size_t)DD * AA * 2);
  unsigned short* WkT = (unsigned short*)alloc((size_t)DD * AA * 2);
  unsigned short* WvT = (unsigned short*)alloc((size_t)DD * AA * 2);
  unsigned short* WoT = (unsigned short*)alloc((size_t)AA * PP * 2);
  unsigned short* x_bf = model_bf;  // reuse: model_bf dead after the Q projection

  cast_bf16_kernel<<<2048, 256, 0, stream>>>(model, model_bf, MB_T * DD / 4);
  cast_bf16_kernel<<<1024, 256, 0, stream>>>(ctx, ctx_bf, CC * DD / 4);

  dim3 tg(16, 16);
  transpose_cast_kernel<<<tg, 256, 0, stream>>>(Wq, WqT, DD, AA);
  transpose_cast_kernel<<<tg, 256, 0, stream>>>(Wk, WkT, DD, AA);
  transpose_cast_kernel<<<tg, 256, 0, stream>>>(Wv, WvT, DD, AA);
  transpose_cast_kernel<<<tg, 256, 0, stream>>>(Wo, WoT, AA, PP);

  const float scale = 0.04419417382415922f;  // 1/sqrt(512)
  // q = (model @ Wq + bq) * scale  -> bf16 [16384][512]
  gemm_bt_kernel<0><<<dim3(AA / 128, MB_T / 128), 256, 0, stream>>>(
      model_bf, WqT, bq, q_bf, MB_T, AA, DD, scale);
  // k = ctx @ Wk + bk -> bf16 [4096][512]
  gemm_bt_kernel<0><<<dim3(AA / 128, CC / 128), 256, 0, stream>>>(
      ctx_bf, WkT, bk, k_bf, CC, AA, DD, 1.0f);
  // vT = (ctx @ Wv + bv)^T -> bf16 [512][4096]
  gemm_bt_kernel<1><<<dim3(AA / 128, CC / 128), 256, 0, stream>>>(
      ctx_bf, WvT, bv, vT_bf, CC, AA, DD, 1.0f);

  // flash attention: x [16384][512] bf16
  flash_kernel<<<MB_T / 32, 512, 0, stream>>>(q_bf, k_bf, vT_bf, x_bf);

  // out = x @ Wo + bo -> f32 [16384][512]
  gemm_bt_kernel<2><<<dim3(PP / 128, MB_T / 128), 256, 0, stream>>>(
      x_bf, WoT, bo, out, MB_T, PP, AA, 1.0f);
}

// Round 2
// 429.399 us; speedup vs baseline: 1.4649x; 1.4649x over previous
//
#include <hip/hip_runtime.h>

// Problem dims
#define MB_T 16384   // B*T
#define DD   512     // model hidden
#define CC   4096    // context entries
#define AA   512     // attn dim
#define PP   512     // out dim

typedef __attribute__((ext_vector_type(4))) float f32x4;
typedef __attribute__((ext_vector_type(8))) short short8;

#define MFMA16(a, b, c) __builtin_amdgcn_mfma_f32_16x16x32_bf16((a), (b), (c), 0, 0, 0)

__device__ __forceinline__ unsigned short f2bf(float f) {
  union { float f; unsigned int u; } cv; cv.f = f;
  unsigned int u = cv.u;
  return (unsigned short)((u + 0x7FFFu + ((u >> 16) & 1u)) >> 16);
}

// async global->LDS, 16B per lane; lds dest must be wave-uniform base (+lane*16 by HW)
__device__ __forceinline__ void gload16(const unsigned short* g, unsigned short* l) {
  __builtin_amdgcn_global_load_lds(
      (const __attribute__((address_space(1))) unsigned int*)g,
      (__attribute__((address_space(3))) unsigned int*)l, 16, 0, 0);
}

// ---------------- cast fp32 -> bf16, x4 vectorized ----------------
__global__ void cast_bf16_kernel(const float* __restrict__ in,
                                 unsigned short* __restrict__ out, int n4) {
  int i = blockIdx.x * blockDim.x + threadIdx.x;
  int stride = gridDim.x * blockDim.x;
  for (; i < n4; i += stride) {
    float4 v = reinterpret_cast<const float4*>(in)[i];
    ushort4 o;
    o.x = f2bf(v.x); o.y = f2bf(v.y); o.z = f2bf(v.z); o.w = f2bf(v.w);
    reinterpret_cast<ushort4*>(out)[i] = o;
  }
}

// ---------------- W [rows][cols] f32 -> WT [cols][rows] bf16 ----------------
__global__ __launch_bounds__(256) void transpose_cast_kernel(
    const float* __restrict__ W, unsigned short* __restrict__ WT, int rows, int cols) {
  __shared__ float t_s[32][33];
  int bi = blockIdx.y * 32, bj = blockIdx.x * 32;
  int r = threadIdx.x >> 3, c4 = (threadIdx.x & 7) * 4;
  float4 v = *reinterpret_cast<const float4*>(W + (size_t)(bi + r) * cols + bj + c4);
  t_s[r][c4 + 0] = v.x; t_s[r][c4 + 1] = v.y;
  t_s[r][c4 + 2] = v.z; t_s[r][c4 + 3] = v.w;
  __syncthreads();
  ushort4 o;
  o.x = f2bf(t_s[c4 + 0][r]);
  o.y = f2bf(t_s[c4 + 1][r]);
  o.z = f2bf(t_s[c4 + 2][r]);
  o.w = f2bf(t_s[c4 + 3][r]);
  *reinterpret_cast<ushort4*>(WT + (size_t)(bj + r) * rows + bi + c4) = o;
}

// ---------------- m97-style 128x128 GEMM: C = f(A @ BT^T) ----------------
// A [M][K] bf16, BT [N][K] bf16. BK=32, 4 waves (2x2), global_load_lds staging.
// MODE 0: C bf16 [M][N] = (acc+bias)*alpha
// MODE 1: C bf16 transposed [N][M] = acc+bias
// MODE 2: C f32 [M][N] = acc+bias
// MODE 3: C bf16 [M][N] = exp(acc); atomicAdd row sums into rowsum_out
// MODE 4: C bf16 [M][N] = acc / rowsum_in[row]
template <int MODE>
__global__ __launch_bounds__(256) void gemm97_kernel(
    const unsigned short* __restrict__ A, const unsigned short* __restrict__ BT,
    const float* __restrict__ bias, const float* __restrict__ rowsum_in,
    float* __restrict__ rowsum_out, void* __restrict__ Cout,
    int M, int N, int K, float alpha) {
  __shared__ unsigned short a_s[4096];  // [128][32] linear (8 KB)
  __shared__ unsigned short b_s[4096];
  const int tid = threadIdx.x;
  const int lane = tid & 63, wid = tid >> 6;
  const int hq = lane >> 4, lq = lane & 15;
  const int wm = wid >> 1, wn = wid & 1;

  // XCD-chunked swizzle (total blocks divisible by 8 for all our launches)
  const int gx = gridDim.x;
  const int nwg = gx * gridDim.y;
  const int orig = blockIdx.y * gx + blockIdx.x;
  const int swz = (orig & 7) * (nwg >> 3) + (orig >> 3);
  const int bx = swz % gx, by = swz / gx;
  const int brow = by * 128, bcol = bx * 128;

  const unsigned short* ap = A + (size_t)(brow + (tid >> 2)) * K + (tid & 3) * 8;
  const unsigned short* bp = BT + (size_t)(bcol + (tid >> 2)) * K + (tid & 3) * 8;
  const size_t rstep = (size_t)64 * K;
  unsigned short* adst = a_s + wid * 512;  // wave-uniform LDS bases
  unsigned short* bdst = b_s + wid * 512;

  f32x4 acc[4][4] = {};
  for (int k0 = 0; k0 < K; k0 += 32) {
    gload16(ap + k0, adst);
    gload16(ap + rstep + k0, adst + 2048);
    gload16(bp + k0, bdst);
    gload16(bp + rstep + k0, bdst + 2048);
    __syncthreads();
    short8 af[4], bfv[4];
#pragma unroll
    for (int mf = 0; mf < 4; ++mf)
      af[mf] = *reinterpret_cast<const short8*>(&a_s[(wm * 64 + mf * 16 + lq) * 32 + hq * 8]);
#pragma unroll
    for (int nf = 0; nf < 4; ++nf)
      bfv[nf] = *reinterpret_cast<const short8*>(&b_s[(wn * 64 + nf * 16 + lq) * 32 + hq * 8]);
#pragma unroll
    for (int mf = 0; mf < 4; ++mf)
#pragma unroll
      for (int nf = 0; nf < 4; ++nf)
        acc[mf][nf] = MFMA16(af[mf], bfv[nf], acc[mf][nf]);
    __syncthreads();
  }

  if (MODE == 3) {
    // exp epilogue + row-sum atomics
#pragma unroll
    for (int mf = 0; mf < 4; ++mf)
#pragma unroll
      for (int i = 0; i < 4; ++i) {
        const int rowg = brow + wm * 64 + mf * 16 + hq * 4 + i;
        float s = 0.f;
#pragma unroll
        for (int nf = 0; nf < 4; ++nf) {
          float p = __expf(acc[mf][nf][i]);
          s += p;
          ((unsigned short*)Cout)[(size_t)rowg * N + bcol + wn * 64 + nf * 16 + lq] = f2bf(p);
        }
        s += __shfl_xor(s, 1);
        s += __shfl_xor(s, 2);
        s += __shfl_xor(s, 4);
        s += __shfl_xor(s, 8);
        if (lq == 0) atomicAdd(rowsum_out + rowg, s);
      }
  } else if (MODE == 4) {
#pragma unroll
    for (int mf = 0; mf < 4; ++mf)
#pragma unroll
      for (int i = 0; i < 4; ++i) {
        const int rowg = brow + wm * 64 + mf * 16 + hq * 4 + i;
        const float inv = 1.0f / rowsum_in[rowg];
#pragma unroll
        for (int nf = 0; nf < 4; ++nf)
          ((unsigned short*)Cout)[(size_t)rowg * N + bcol + wn * 64 + nf * 16 + lq] =
              f2bf(acc[mf][nf][i] * inv);
      }
  } else if (MODE == 1) {
#pragma unroll
    for (int nf = 0; nf < 4; ++nf) {
      const int colg = bcol + wn * 64 + nf * 16 + lq;
      const float bv = bias[colg];
#pragma unroll
      for (int mf = 0; mf < 4; ++mf) {
        const int rowg0 = brow + wm * 64 + mf * 16 + hq * 4;
        ushort4 pk;
        pk.x = f2bf(acc[mf][nf][0] + bv);
        pk.y = f2bf(acc[mf][nf][1] + bv);
        pk.z = f2bf(acc[mf][nf][2] + bv);
        pk.w = f2bf(acc[mf][nf][3] + bv);
        *reinterpret_cast<ushort4*>((unsigned short*)Cout + (size_t)colg * M + rowg0) = pk;
      }
    }
  } else {
#pragma unroll
    for (int nf = 0; nf < 4; ++nf) {
      const int colg = bcol + wn * 64 + nf * 16 + lq;
      const float bv = bias[colg];
#pragma unroll
      for (int mf = 0; mf < 4; ++mf) {
        const int rowg0 = brow + wm * 64 + mf * 16 + hq * 4;
#pragma unroll
        for (int i = 0; i < 4; ++i) {
          float v = (acc[mf][nf][i] + bv) * alpha;
          if (MODE == 0)
            ((unsigned short*)Cout)[(size_t)(rowg0 + i) * N + colg] = f2bf(v);
          else
            ((float*)Cout)[(size_t)(rowg0 + i) * N + colg] = v;
        }
      }
    }
  }
}

extern "C" void kernel_launch(void* const* d_in, const int* in_sizes, int n_in,
                              void* d_out, int out_size, void* d_ws, size_t ws_size,
                              hipStream_t stream) {
  const float* model = (const float*)d_in[0];
  const float* ctx   = (const float*)d_in[1];
  const float* Wq = (const float*)d_in[2]; const float* bq = (const float*)d_in[3];
  const float* Wk = (const float*)d_in[4]; const float* bk = (const float*)d_in[5];
  const float* Wv = (const float*)d_in[6]; const float* bv = (const float*)d_in[7];
  const float* Wo = (const float*)d_in[8]; const float* bo = (const float*)d_in[9];
  float* out = (float*)d_out;

  char* ws = (char*)d_ws;
  size_t off = 0;
  auto alloc = [&](size_t bytes) -> void* {
    void* p = ws + off;
    off += (bytes + 255) & ~(size_t)255;
    return p;
  };
  unsigned short* model_bf = (unsigned short*)alloc((size_t)MB_T * DD * 2);
  unsigned short* ctx_bf   = (unsigned short*)alloc((size_t)CC * DD * 2);
  unsigned short* q_bf     = (unsigned short*)alloc((size_t)MB_T * AA * 2);
  unsigned short* k_bf     = (unsigned short*)alloc((size_t)CC * AA * 2);
  unsigned short* vT_bf    = (unsigned short*)alloc((size_t)AA * CC * 2);
  unsigned short* WqT = (unsigned short*)alloc((size_t)DD * AA * 2);
  unsigned short* WkT = (unsigned short*)alloc((size_t)DD * AA * 2);
  unsigned short* WvT = (unsigned short*)alloc((size_t)DD * AA * 2);
  unsigned short* WoT = (unsigned short*)alloc((size_t)AA * PP * 2);
  float*          lsum = (float*)alloc((size_t)MB_T * 4);
  unsigned short* P_bf = (unsigned short*)alloc((size_t)MB_T * CC * 2);  // 128 MiB
  unsigned short* x_bf = model_bf;  // reuse: model_bf dead after the Q projection

  cast_bf16_kernel<<<2048, 256, 0, stream>>>(model, model_bf, MB_T * DD / 4);
  cast_bf16_kernel<<<1024, 256, 0, stream>>>(ctx, ctx_bf, CC * DD / 4);

  dim3 tg(16, 16);
  transpose_cast_kernel<<<tg, 256, 0, stream>>>(Wq, WqT, DD, AA);
  transpose_cast_kernel<<<tg, 256, 0, stream>>>(Wk, WkT, DD, AA);
  transpose_cast_kernel<<<tg, 256, 0, stream>>>(Wv, WvT, DD, AA);
  transpose_cast_kernel<<<tg, 256, 0, stream>>>(Wo, WoT, AA, PP);

  const float scale = 0.04419417382415922f;  // 1/sqrt(512)

  // q = (model @ Wq + bq) * scale -> bf16 [16384][512]   (scale folded here)
  gemm97_kernel<0><<<dim3(AA / 128, MB_T / 128), 256, 0, stream>>>(
      model_bf, WqT, bq, nullptr, nullptr, q_bf, MB_T, AA, DD, scale);
  // k = ctx @ Wk + bk -> bf16 [4096][512]
  gemm97_kernel<0><<<dim3(AA / 128, CC / 128), 256, 0, stream>>>(
      ctx_bf, WkT, bk, nullptr, nullptr, k_bf, CC, AA, DD, 1.0f);
  // vT = (ctx @ Wv + bv)^T -> bf16 [512][4096]
  gemm97_kernel<1><<<dim3(AA / 128, CC / 128), 256, 0, stream>>>(
      ctx_bf, WvT, bv, nullptr, nullptr, vT_bf, CC, AA, DD, 1.0f);

  // P = exp(q @ k^T) bf16 [16384][4096]; lsum[m] = sum_c P[m][c]
  hipMemsetAsync(lsum, 0, (size_t)MB_T * 4, stream);
  gemm97_kernel<3><<<dim3(CC / 128, MB_T / 128), 256, 0, stream>>>(
      q_bf, k_bf, nullptr, nullptr, lsum, P_bf, MB_T, CC, AA, 1.0f);

  // x = (P @ v) / lsum -> bf16 [16384][512]
  gemm97_kernel<4><<<dim3(AA / 128, MB_T / 128), 256, 0, stream>>>(
      P_bf, vT_bf, nullptr, lsum, nullptr, x_bf, MB_T, AA, CC, 1.0f);

  // out = x @ Wo + bo -> f32 [16384][512]
  gemm97_kernel<2><<<dim3(PP / 128, MB_T / 128), 256, 0, stream>>>(
      x_bf, WoT, bo, nullptr, nullptr, out, MB_T, PP, AA, 1.0f);
}

// Round 3
// 417.544 us; speedup vs baseline: 1.5065x; 1.0284x over previous
//
#include <hip/hip_runtime.h>

// Problem dims
#define MB_T 16384   // B*T
#define DD   512     // model hidden
#define CC   4096    // context entries
#define AA   512     // attn dim
#define PP   512     // out dim

typedef __attribute__((ext_vector_type(4))) float f32x4;
typedef __attribute__((ext_vector_type(8))) short short8;

#define MFMA16(a, b, c) __builtin_amdgcn_mfma_f32_16x16x32_bf16((a), (b), (c), 0, 0, 0)

__device__ __forceinline__ unsigned short f2bf(float f) {
  union { float f; unsigned int u; } cv; cv.f = f;
  unsigned int u = cv.u;
  return (unsigned short)((u + 0x7FFFu + ((u >> 16) & 1u)) >> 16);
}
__device__ __forceinline__ float bf2f(unsigned short u) {
  union { unsigned int i; float f; } c; c.i = (unsigned int)u << 16; return c.f;
}

// async global->LDS, 16B per lane; lds dest is wave-uniform base (+lane*16 by HW)
__device__ __forceinline__ void gload16(const unsigned short* g, unsigned short* l) {
  __builtin_amdgcn_global_load_lds(
      (const __attribute__((address_space(1))) unsigned int*)g,
      (__attribute__((address_space(3))) unsigned int*)l, 16, 0, 0);
}

// ---------------- cast fp32 -> bf16, x4 vectorized ----------------
__global__ void cast_bf16_kernel(const float* __restrict__ in,
                                 unsigned short* __restrict__ out, int n4) {
  int i = blockIdx.x * blockDim.x + threadIdx.x;
  int stride = gridDim.x * blockDim.x;
  for (; i < n4; i += stride) {
    float4 v = reinterpret_cast<const float4*>(in)[i];
    ushort4 o;
    o.x = f2bf(v.x); o.y = f2bf(v.y); o.z = f2bf(v.z); o.w = f2bf(v.w);
    reinterpret_cast<ushort4*>(out)[i] = o;
  }
}

// ---------------- W [rows][cols] f32 -> WT [cols][rows] bf16 ----------------
__global__ __launch_bounds__(256) void transpose_cast_kernel(
    const float* __restrict__ W, unsigned short* __restrict__ WT, int rows, int cols) {
  __shared__ float t_s[32][33];
  int bi = blockIdx.y * 32, bj = blockIdx.x * 32;
  int r = threadIdx.x >> 3, c4 = (threadIdx.x & 7) * 4;
  float4 v = *reinterpret_cast<const float4*>(W + (size_t)(bi + r) * cols + bj + c4);
  t_s[r][c4 + 0] = v.x; t_s[r][c4 + 1] = v.y;
  t_s[r][c4 + 2] = v.z; t_s[r][c4 + 3] = v.w;
  __syncthreads();
  ushort4 o;
  o.x = f2bf(t_s[c4 + 0][r]);
  o.y = f2bf(t_s[c4 + 1][r]);
  o.z = f2bf(t_s[c4 + 2][r]);
  o.w = f2bf(t_s[c4 + 3][r]);
  *reinterpret_cast<ushort4*>(WT + (size_t)(bj + r) * rows + bi + c4) = o;
}

// ---------------- bqk[c] = scale * dot(k[c,:], bq) ----------------
__global__ __launch_bounds__(256) void rowdot_kernel(
    const unsigned short* __restrict__ k, const float* __restrict__ bq,
    float* __restrict__ outv, float scale) {
  const int lane = threadIdx.x & 63, wid = threadIdx.x >> 6;
  const int row = blockIdx.x * 4 + wid;
  const unsigned short* kr = k + (size_t)row * AA + lane * 8;
  float s = 0.f;
  ushort4 a = *reinterpret_cast<const ushort4*>(kr);
  ushort4 b = *reinterpret_cast<const ushort4*>(kr + 4);
  const float* bqp = bq + lane * 8;
  s += bf2f(a.x) * bqp[0]; s += bf2f(a.y) * bqp[1];
  s += bf2f(a.z) * bqp[2]; s += bf2f(a.w) * bqp[3];
  s += bf2f(b.x) * bqp[4]; s += bf2f(b.y) * bqp[5];
  s += bf2f(b.z) * bqp[6]; s += bf2f(b.w) * bqp[7];
#pragma unroll
  for (int d = 1; d < 64; d <<= 1) s += __shfl_xor(s, d);
  if (lane == 0) outv[row] = s * scale;
}

// ---------------- 2-phase double-buffered 128x128 GEMM ----------------
// A [M][K] bf16, BT [N][K] bf16; BK=32, 4 waves (2x2).
// MODE 0: C bf16 [M][N] = (acc + bias[col]) * alpha   (bias may be null)
// MODE 3: C bf16 [M][N] = exp(acc + colbias[col]); atomicAdd row-sums -> rowsum_out
// MODE 5: C f32  [M][N] = acc / rowsum_in[row] + bias[col]
template <int MODE>
__global__ __launch_bounds__(256) void gemm2p_kernel(
    const unsigned short* __restrict__ A, const unsigned short* __restrict__ BT,
    const float* __restrict__ bias, const float* __restrict__ colbias,
    const float* __restrict__ rowsum_in, float* __restrict__ rowsum_out,
    void* __restrict__ Cout, int M, int N, int K, float alpha) {
  __shared__ unsigned short a_s[2][4096];  // [128][32] linear, double-buffered
  __shared__ unsigned short b_s[2][4096];
  const int tid = threadIdx.x;
  const int lane = tid & 63, wid = tid >> 6;
  const int hq = lane >> 4, lq = lane & 15;
  const int wm = wid >> 1, wn = wid & 1;

  // XCD-chunked swizzle (nwg divisible by 8 for all launches here)
  const int gx = gridDim.x;
  const int nwg = gx * gridDim.y;
  const int orig = blockIdx.y * gx + blockIdx.x;
  const int swz = (orig & 7) * (nwg >> 3) + (orig >> 3);
  const int bx = swz % gx, by = swz / gx;
  const int brow = by * 128, bcol = bx * 128;

  const unsigned short* ap = A + (size_t)(brow + (tid >> 2)) * K + (tid & 3) * 8;
  const unsigned short* bp = BT + (size_t)(bcol + (tid >> 2)) * K + (tid & 3) * 8;
  const size_t rstep = (size_t)64 * K;
  const int ldsoff = wid * 512;  // wave-uniform

  const int nt = K >> 5;
  // prologue: stage tile 0 into buffer 0
  gload16(ap, a_s[0] + ldsoff);
  gload16(ap + rstep, a_s[0] + ldsoff + 2048);
  gload16(bp, b_s[0] + ldsoff);
  gload16(bp + rstep, b_s[0] + ldsoff + 2048);
  __syncthreads();

  f32x4 acc[4][4] = {};
  for (int t = 0; t < nt; ++t) {
    const int cur = t & 1;
    if (t + 1 < nt) {  // issue next-tile staging BEFORE compute (overlaps)
      const int k0 = (t + 1) * 32;
      gload16(ap + k0, a_s[cur ^ 1] + ldsoff);
      gload16(ap + rstep + k0, a_s[cur ^ 1] + ldsoff + 2048);
      gload16(bp + k0, b_s[cur ^ 1] + ldsoff);
      gload16(bp + rstep + k0, b_s[cur ^ 1] + ldsoff + 2048);
    }
    short8 af[4], bfv[4];
#pragma unroll
    for (int mf = 0; mf < 4; ++mf)
      af[mf] = *reinterpret_cast<const short8*>(&a_s[cur][(wm * 64 + mf * 16 + lq) * 32 + hq * 8]);
#pragma unroll
    for (int nf = 0; nf < 4; ++nf)
      bfv[nf] = *reinterpret_cast<const short8*>(&b_s[cur][(wn * 64 + nf * 16 + lq) * 32 + hq * 8]);
#pragma unroll
    for (int mf = 0; mf < 4; ++mf)
#pragma unroll
      for (int nf = 0; nf < 4; ++nf)
        acc[mf][nf] = MFMA16(af[mf], bfv[nf], acc[mf][nf]);
    if (t + 1 < nt) __syncthreads();  // covers: stage(t+1) landed, all reads of buf(t) done
  }

  if (MODE == 3) {
    float cb[4];
#pragma unroll
    for (int nf = 0; nf < 4; ++nf) cb[nf] = colbias[bcol + wn * 64 + nf * 16 + lq];
#pragma unroll
    for (int mf = 0; mf < 4; ++mf)
#pragma unroll
      for (int i = 0; i < 4; ++i) {
        const int rowg = brow + wm * 64 + mf * 16 + hq * 4 + i;
        float s = 0.f;
#pragma unroll
        for (int nf = 0; nf < 4; ++nf) {
          float p = __expf(acc[mf][nf][i] + cb[nf]);
          s += p;
          ((unsigned short*)Cout)[(size_t)rowg * N + bcol + wn * 64 + nf * 16 + lq] = f2bf(p);
        }
        s += __shfl_xor(s, 1);
        s += __shfl_xor(s, 2);
        s += __shfl_xor(s, 4);
        s += __shfl_xor(s, 8);
        if (lq == 0) atomicAdd(rowsum_out + rowg, s);
      }
  } else if (MODE == 5) {
#pragma unroll
    for (int mf = 0; mf < 4; ++mf)
#pragma unroll
      for (int i = 0; i < 4; ++i) {
        const int rowg = brow + wm * 64 + mf * 16 + hq * 4 + i;
        const float inv = 1.0f / rowsum_in[rowg];
#pragma unroll
        for (int nf = 0; nf < 4; ++nf) {
          const int colg = bcol + wn * 64 + nf * 16 + lq;
          ((float*)Cout)[(size_t)rowg * N + colg] = acc[mf][nf][i] * inv + bias[colg];
        }
      }
  } else {
#pragma unroll
    for (int nf = 0; nf < 4; ++nf) {
      const int colg = bcol + wn * 64 + nf * 16 + lq;
      const float bv = bias ? bias[colg] : 0.f;
#pragma unroll
      for (int mf = 0; mf < 4; ++mf) {
        const int rowg0 = brow + wm * 64 + mf * 16 + hq * 4;
#pragma unroll
        for (int i = 0; i < 4; ++i)
          ((unsigned short*)Cout)[(size_t)(rowg0 + i) * N + colg] =
              f2bf((acc[mf][nf][i] + bv) * alpha);
      }
    }
  }
}

extern "C" void kernel_launch(void* const* d_in, const int* in_sizes, int n_in,
                              void* d_out, int out_size, void* d_ws, size_t ws_size,
                              hipStream_t stream) {
  const float* model = (const float*)d_in[0];
  const float* ctx   = (const float*)d_in[1];
  const float* Wq = (const float*)d_in[2]; const float* bq = (const float*)d_in[3];
  const float* Wk = (const float*)d_in[4]; const float* bk = (const float*)d_in[5];
  const float* Wv = (const float*)d_in[6]; const float* bv = (const float*)d_in[7];
  const float* Wo = (const float*)d_in[8]; const float* bo = (const float*)d_in[9];
  float* out = (float*)d_out;

  char* ws = (char*)d_ws;
  size_t off = 0;
  auto alloc = [&](size_t bytes) -> void* {
    void* p = ws + off;
    off += (bytes + 255) & ~(size_t)255;
    return p;
  };
  unsigned short* model_bf = (unsigned short*)alloc((size_t)MB_T * DD * 2);
  unsigned short* ctx_bf   = (unsigned short*)alloc((size_t)CC * DD * 2);
  unsigned short* k_bf     = (unsigned short*)alloc((size_t)CC * AA * 2);
  unsigned short* v_bf     = (unsigned short*)alloc((size_t)CC * AA * 2);
  unsigned short* Wq_bf    = (unsigned short*)alloc((size_t)DD * AA * 2);  // natural [D][A]
  unsigned short* WkT = (unsigned short*)alloc((size_t)DD * AA * 2);
  unsigned short* WvT = (unsigned short*)alloc((size_t)DD * AA * 2);
  unsigned short* WoT = (unsigned short*)alloc((size_t)AA * PP * 2);
  unsigned short* KqT_bf = (unsigned short*)alloc((size_t)CC * DD * 2);  // [C][D]
  unsigned short* W2T_bf = (unsigned short*)alloc((size_t)PP * CC * 2);  // [P][C]
  float* bqk  = (float*)alloc((size_t)CC * 4);
  float* lsum = (float*)alloc((size_t)MB_T * 4);
  unsigned short* P_bf = (unsigned short*)alloc((size_t)MB_T * CC * 2);  // 128 MiB

  const float scale = 0.04419417382415922f;  // 1/sqrt(512)

  cast_bf16_kernel<<<2048, 256, 0, stream>>>(model, model_bf, MB_T * DD / 4);
  cast_bf16_kernel<<<1024, 256, 0, stream>>>(ctx, ctx_bf, CC * DD / 4);
  cast_bf16_kernel<<<256, 256, 0, stream>>>(Wq, Wq_bf, DD * AA / 4);

  dim3 tg(16, 16);
  transpose_cast_kernel<<<tg, 256, 0, stream>>>(Wk, WkT, DD, AA);
  transpose_cast_kernel<<<tg, 256, 0, stream>>>(Wv, WvT, DD, AA);
  transpose_cast_kernel<<<tg, 256, 0, stream>>>(Wo, WoT, AA, PP);

  // k = ctx @ Wk + bk -> bf16 [4096][512]
  gemm2p_kernel<0><<<dim3(AA / 128, CC / 128), 256, 0, stream>>>(
      ctx_bf, WkT, bk, nullptr, nullptr, nullptr, k_bf, CC, AA, DD, 1.0f);
  // v = ctx @ Wv + bv -> bf16 [4096][512]
  gemm2p_kernel<0><<<dim3(AA / 128, CC / 128), 256, 0, stream>>>(
      ctx_bf, WvT, bv, nullptr, nullptr, nullptr, v_bf, CC, AA, DD, 1.0f);

  // KqT = scale * (k @ Wq^T) -> bf16 [4096][512]  (Wq natural layout == BT)
  gemm2p_kernel<0><<<dim3(DD / 128, CC / 128), 256, 0, stream>>>(
      k_bf, Wq_bf, nullptr, nullptr, nullptr, nullptr, KqT_bf, CC, DD, AA, scale);
  // bqk[c] = scale * k[c]·bq
  rowdot_kernel<<<CC / 4, 256, 0, stream>>>(k_bf, bq, bqk, scale);

  // W2T = (v @ Wo)^T = WoT @ v^T -> bf16 [512][4096]
  gemm2p_kernel<0><<<dim3(CC / 128, PP / 128), 256, 0, stream>>>(
      WoT, v_bf, nullptr, nullptr, nullptr, nullptr, W2T_bf, PP, CC, AA, 1.0f);

  // P = exp(model @ KqT^T + bqk[col]) -> bf16 [16384][4096]; lsum = row sums
  hipMemsetAsync(lsum, 0, (size_t)MB_T * 4, stream);
  gemm2p_kernel<3><<<dim3(CC / 128, MB_T / 128), 256, 0, stream>>>(
      model_bf, KqT_bf, nullptr, bqk, nullptr, lsum, P_bf, MB_T, CC, DD, 1.0f);

  // out = P @ W2T^T / lsum + bo -> f32 [16384][512]
  gemm2p_kernel<5><<<dim3(PP / 128, MB_T / 128), 256, 0, stream>>>(
      P_bf, W2T_bf, bo, nullptr, lsum, nullptr, out, MB_T, PP, CC, 1.0f);
}

// Round 4
// 410.521 us; speedup vs baseline: 1.5322x; 1.0171x over previous
//
#include <hip/hip_runtime.h>

// Problem dims
#define MB_T 16384   // B*T
#define DD   512     // model hidden
#define CC   4096    // context entries
#define AA   512     // attn dim
#define PP   512     // out dim

typedef __attribute__((ext_vector_type(4))) float f32x4;
typedef __attribute__((ext_vector_type(8))) short short8;

#define MFMA16(a, b, c) __builtin_amdgcn_mfma_f32_16x16x32_bf16((a), (b), (c), 0, 0, 0)

__device__ __forceinline__ unsigned short f2bf(float f) {
  union { float f; unsigned int u; } cv; cv.f = f;
  unsigned int u = cv.u;
  return (unsigned short)((u + 0x7FFFu + ((u >> 16) & 1u)) >> 16);
}
__device__ __forceinline__ float bf2f(unsigned short u) {
  union { unsigned int i; float f; } c; c.i = (unsigned int)u << 16; return c.f;
}

// async global->LDS, 16B per lane; lds dest is wave-uniform base (+lane*16 by HW)
__device__ __forceinline__ void gload16(const unsigned short* g, unsigned short* l) {
  __builtin_amdgcn_global_load_lds(
      (const __attribute__((address_space(1))) unsigned int*)g,
      (__attribute__((address_space(3))) unsigned int*)l, 16, 0, 0);
}

// ---------------- cast fp32 -> bf16, x4 vectorized ----------------
__global__ void cast_bf16_kernel(const float* __restrict__ in,
                                 unsigned short* __restrict__ out, int n4) {
  int i = blockIdx.x * blockDim.x + threadIdx.x;
  int stride = gridDim.x * blockDim.x;
  for (; i < n4; i += stride) {
    float4 v = reinterpret_cast<const float4*>(in)[i];
    ushort4 o;
    o.x = f2bf(v.x); o.y = f2bf(v.y); o.z = f2bf(v.z); o.w = f2bf(v.w);
    reinterpret_cast<ushort4*>(out)[i] = o;
  }
}

// ---------------- W [rows][cols] f32 -> WT [cols][rows] bf16 ----------------
__global__ __launch_bounds__(256) void transpose_cast_kernel(
    const float* __restrict__ W, unsigned short* __restrict__ WT, int rows, int cols) {
  __shared__ float t_s[32][33];
  int bi = blockIdx.y * 32, bj = blockIdx.x * 32;
  int r = threadIdx.x >> 3, c4 = (threadIdx.x & 7) * 4;
  float4 v = *reinterpret_cast<const float4*>(W + (size_t)(bi + r) * cols + bj + c4);
  t_s[r][c4 + 0] = v.x; t_s[r][c4 + 1] = v.y;
  t_s[r][c4 + 2] = v.z; t_s[r][c4 + 3] = v.w;
  __syncthreads();
  ushort4 o;
  o.x = f2bf(t_s[c4 + 0][r]);
  o.y = f2bf(t_s[c4 + 1][r]);
  o.z = f2bf(t_s[c4 + 2][r]);
  o.w = f2bf(t_s[c4 + 3][r]);
  *reinterpret_cast<ushort4*>(WT + (size_t)(bj + r) * rows + bi + c4) = o;
}

// ---------------- out[r] = scale * dot(mat[r,0:512], vec) ----------------
__global__ __launch_bounds__(256) void rowdot_kernel(
    const unsigned short* __restrict__ mat, const float* __restrict__ vec,
    float* __restrict__ outv, float scale) {
  const int lane = threadIdx.x & 63, wid = threadIdx.x >> 6;
  const int row = blockIdx.x * 4 + wid;
  const unsigned short* kr = mat + (size_t)row * 512 + lane * 8;
  float s = 0.f;
  ushort4 a = *reinterpret_cast<const ushort4*>(kr);
  ushort4 b = *reinterpret_cast<const ushort4*>(kr + 4);
  const float* bqp = vec + lane * 8;
  s += bf2f(a.x) * bqp[0]; s += bf2f(a.y) * bqp[1];
  s += bf2f(a.z) * bqp[2]; s += bf2f(a.w) * bqp[3];
  s += bf2f(b.x) * bqp[4]; s += bf2f(b.y) * bqp[5];
  s += bf2f(b.z) * bqp[6]; s += bf2f(b.w) * bqp[7];
#pragma unroll
  for (int d = 1; d < 64; d <<= 1) s += __shfl_xor(s, d);
  if (lane == 0) outv[row] = s * scale;
}

// ---------------- 2-phase double-buffered 128x128 GEMM (small jobs) ----------------
// MODE 0: C bf16 [M][N] = (acc + bias[col]) * alpha   (bias may be null)
// MODE 1: C bf16 transposed [N][M] = acc + bias[col]
template <int MODE>
__global__ __launch_bounds__(256) void gemm2p_kernel(
    const unsigned short* __restrict__ A, const unsigned short* __restrict__ BT,
    const float* __restrict__ bias, void* __restrict__ Cout,
    int M, int N, int K, float alpha) {
  __shared__ unsigned short a_s[2][4096];  // [128][32] linear, double-buffered
  __shared__ unsigned short b_s[2][4096];
  const int tid = threadIdx.x;
  const int lane = tid & 63, wid = tid >> 6;
  const int hq = lane >> 4, lq = lane & 15;
  const int wm = wid >> 1, wn = wid & 1;

  const int gx = gridDim.x;
  const int nwg = gx * gridDim.y;
  const int orig = blockIdx.y * gx + blockIdx.x;
  const int swz = (orig & 7) * (nwg >> 3) + (orig >> 3);
  const int bx = swz % gx, by = swz / gx;
  const int brow = by * 128, bcol = bx * 128;

  const unsigned short* ap = A + (size_t)(brow + (tid >> 2)) * K + (tid & 3) * 8;
  const unsigned short* bp = BT + (size_t)(bcol + (tid >> 2)) * K + (tid & 3) * 8;
  const size_t rstep = (size_t)64 * K;
  const int ldsoff = wid * 512;

  const int nt = K >> 5;
  gload16(ap, a_s[0] + ldsoff);
  gload16(ap + rstep, a_s[0] + ldsoff + 2048);
  gload16(bp, b_s[0] + ldsoff);
  gload16(bp + rstep, b_s[0] + ldsoff + 2048);
  __syncthreads();

  f32x4 acc[4][4] = {};
  for (int t = 0; t < nt; ++t) {
    const int cur = t & 1;
    if (t + 1 < nt) {
      const int k0 = (t + 1) * 32;
      gload16(ap + k0, a_s[cur ^ 1] + ldsoff);
      gload16(ap + rstep + k0, a_s[cur ^ 1] + ldsoff + 2048);
      gload16(bp + k0, b_s[cur ^ 1] + ldsoff);
      gload16(bp + rstep + k0, b_s[cur ^ 1] + ldsoff + 2048);
    }
    short8 af[4], bfv[4];
#pragma unroll
    for (int mf = 0; mf < 4; ++mf)
      af[mf] = *reinterpret_cast<const short8*>(&a_s[cur][(wm * 64 + mf * 16 + lq) * 32 + hq * 8]);
#pragma unroll
    for (int nf = 0; nf < 4; ++nf)
      bfv[nf] = *reinterpret_cast<const short8*>(&b_s[cur][(wn * 64 + nf * 16 + lq) * 32 + hq * 8]);
#pragma unroll
    for (int mf = 0; mf < 4; ++mf)
#pragma unroll
      for (int nf = 0; nf < 4; ++nf)
        acc[mf][nf] = MFMA16(af[mf], bfv[nf], acc[mf][nf]);
    if (t + 1 < nt) __syncthreads();
  }

  if (MODE == 1) {
#pragma unroll
    for (int nf = 0; nf < 4; ++nf) {
      const int colg = bcol + wn * 64 + nf * 16 + lq;
      const float bv = bias ? bias[colg] : 0.f;
#pragma unroll
      for (int mf = 0; mf < 4; ++mf) {
        const int rowg0 = brow + wm * 64 + mf * 16 + hq * 4;
        ushort4 pk;
        pk.x = f2bf(acc[mf][nf][0] + bv);
        pk.y = f2bf(acc[mf][nf][1] + bv);
        pk.z = f2bf(acc[mf][nf][2] + bv);
        pk.w = f2bf(acc[mf][nf][3] + bv);
        *reinterpret_cast<ushort4*>((unsigned short*)Cout + (size_t)colg * M + rowg0) = pk;
      }
    }
  } else {
#pragma unroll
    for (int nf = 0; nf < 4; ++nf) {
      const int colg = bcol + wn * 64 + nf * 16 + lq;
      const float bv = bias ? bias[colg] : 0.f;
#pragma unroll
      for (int mf = 0; mf < 4; ++mf) {
        const int rowg0 = brow + wm * 64 + mf * 16 + hq * 4;
#pragma unroll
        for (int i = 0; i < 4; ++i)
          ((unsigned short*)Cout)[(size_t)(rowg0 + i) * N + colg] =
              f2bf((acc[mf][nf][i] + bv) * alpha);
      }
    }
  }
}

// ---------------- deep-pipelined 128x128 GEMM, BK=64, swizzled LDS ----------------
// counted vmcnt: stage t+2 at tail of iter t, wait vmcnt(8) -> tile t+1 ready,
// t+2's 8 loads stay in flight across the barrier.
// MODE 3: C bf16 [M][N] = exp(acc + colbias[col]); atomicAdd row-sums -> rowsum_out
// MODE 5: C f32  [M][N] = acc / rowsum_in[row] + bias[col]
template <int MODE>
__global__ __launch_bounds__(256, 2) void gemm_dp_kernel(
    const unsigned short* __restrict__ A, const unsigned short* __restrict__ BT,
    const float* __restrict__ bias, const float* __restrict__ colbias,
    const float* __restrict__ rowsum_in, float* __restrict__ rowsum_out,
    void* __restrict__ Cout, int M, int N, int K) {
  __shared__ unsigned short a_s[2][8192];  // [buf][128 rows][64 cols], XOR-swizzled chunks
  __shared__ unsigned short b_s[2][8192];
  const int tid = threadIdx.x;
  const int lane = tid & 63, wid = tid >> 6;
  const int hq = lane >> 4, lq = lane & 15;
  const int wm = wid >> 1, wn = wid & 1;

  const int gx = gridDim.x;
  const int nwg = gx * gridDim.y;
  const int orig = blockIdx.y * gx + blockIdx.x;
  const int swz = (orig & 7) * (nwg >> 3) + (orig >> 3);
  const int bx = swz % gx, by = swz / gx;
  const int brow = by * 128, bcol = bx * 128;

  // staging: LDS written linearly (gload_lds); SOURCE column pre-swizzled so that
  // LDS chunk pc at row r holds logical chunk pc ^ (r&7)
  const int srow = tid >> 3;                       // 0..31
  const int schunk = (tid & 7) ^ (srow & 7);       // pre-swizzled 16B chunk
  const unsigned short* agp = A + (size_t)(brow + srow) * K + schunk * 8;
  const unsigned short* bgp = BT + (size_t)(bcol + srow) * K + schunk * 8;
  const size_t row32 = (size_t)32 * K;
  const int ldst = wid * 512;  // wave-uniform dest offset inside each 2048-elem issue block

  const int nt = K >> 6;
  // prologue: stage tiles 0 and 1
#pragma unroll
  for (int j = 0; j < 4; ++j) {
    gload16(agp + j * row32, &a_s[0][j * 2048 + ldst]);
    gload16(bgp + j * row32, &b_s[0][j * 2048 + ldst]);
  }
#pragma unroll
  for (int j = 0; j < 4; ++j) {
    gload16(agp + j * row32 + 64, &a_s[1][j * 2048 + ldst]);
    gload16(bgp + j * row32 + 64, &b_s[1][j * 2048 + ldst]);
  }
  asm volatile("s_waitcnt vmcnt(8)" ::: "memory");  // tile0 landed; tile1 in flight
  __builtin_amdgcn_s_barrier();

  // swizzled read offsets: row r, khalf kh, chunk = (kh*4+hq) ^ (lq&7)
  const int aoff = (wm * 64 + lq) * 64;
  const int boff = (wn * 64 + lq) * 64;
  const int cx0 = ((hq) ^ (lq & 7)) * 8;
  const int cx1 = ((4 + hq) ^ (lq & 7)) * 8;

  f32x4 acc[4][4] = {};
  for (int t = 0; t < nt; ++t) {
    const int cur = t & 1;
    const unsigned short* as0 = a_s[cur];
    const unsigned short* bs0 = b_s[cur];
    short8 ar[2][2], br[4][2];
    // phase 0: A frags 0,1 + all 4 B frags (12 ds_read_b128)
#pragma unroll
    for (int f = 0; f < 2; ++f) {
      ar[f][0] = *reinterpret_cast<const short8*>(as0 + aoff + f * 1024 + cx0);
      ar[f][1] = *reinterpret_cast<const short8*>(as0 + aoff + f * 1024 + cx1);
    }
#pragma unroll
    for (int f = 0; f < 4; ++f) {
      br[f][0] = *reinterpret_cast<const short8*>(bs0 + boff + f * 1024 + cx0);
      br[f][1] = *reinterpret_cast<const short8*>(bs0 + boff + f * 1024 + cx1);
    }
    __builtin_amdgcn_s_setprio(1);
#pragma unroll
    for (int f = 0; f < 2; ++f)
#pragma unroll
      for (int n = 0; n < 4; ++n) {
        acc[f][n] = MFMA16(ar[f][0], br[n][0], acc[f][n]);
        acc[f][n] = MFMA16(ar[f][1], br[n][1], acc[f][n]);
      }
    __builtin_amdgcn_s_setprio(0);
    __builtin_amdgcn_s_barrier();
    // phase 1: A frags 2,3 (4 ds_read_b128), reuse B regs
#pragma unroll
    for (int f = 0; f < 2; ++f) {
      ar[f][0] = *reinterpret_cast<const short8*>(as0 + aoff + (f + 2) * 1024 + cx0);
      ar[f][1] = *reinterpret_cast<const short8*>(as0 + aoff + (f + 2) * 1024 + cx1);
    }
    __builtin_amdgcn_s_setprio(1);
#pragma unroll
    for (int f = 0; f < 2; ++f)
#pragma unroll
      for (int n = 0; n < 4; ++n) {
        acc[f + 2][n] = MFMA16(ar[f][0], br[n][0], acc[f + 2][n]);
        acc[f + 2][n] = MFMA16(ar[f][1], br[n][1], acc[f + 2][n]);
      }
    __builtin_amdgcn_s_setprio(0);
    __builtin_amdgcn_s_barrier();  // all waves done reading buf[cur] -> free to overwrite
    // tail: stage tile t+2 into buf[cur]; counted wait for tile t+1
    if (t + 2 < nt) {
      const size_t k0 = (size_t)(t + 2) * 64;
#pragma unroll
      for (int j = 0; j < 4; ++j) {
        gload16(agp + j * row32 + k0, &a_s[cur][j * 2048 + ldst]);
        gload16(bgp + j * row32 + k0, &b_s[cur][j * 2048 + ldst]);
      }
      asm volatile("s_waitcnt vmcnt(8)" ::: "memory");
      __builtin_amdgcn_s_barrier();
    } else if (t + 1 < nt) {
      asm volatile("s_waitcnt vmcnt(0)" ::: "memory");
      __builtin_amdgcn_s_barrier();
    }
  }

  if (MODE == 3) {
    float cb[4];
#pragma unroll
    for (int nf = 0; nf < 4; ++nf) cb[nf] = colbias[bcol + wn * 64 + nf * 16 + lq];
#pragma unroll
    for (int mf = 0; mf < 4; ++mf)
#pragma unroll
      for (int i = 0; i < 4; ++i) {
        const int rowg = brow + wm * 64 + mf * 16 + hq * 4 + i;
        float s = 0.f;
#pragma unroll
        for (int nf = 0; nf < 4; ++nf) {
          float p = __expf(acc[mf][nf][i] + cb[nf]);
          s += p;
          ((unsigned short*)Cout)[(size_t)rowg * N + bcol + wn * 64 + nf * 16 + lq] = f2bf(p);
        }
        s += __shfl_xor(s, 1);
        s += __shfl_xor(s, 2);
        s += __shfl_xor(s, 4);
        s += __shfl_xor(s, 8);
        if (lq == 0) atomicAdd(rowsum_out + rowg, s);
      }
  } else {
#pragma unroll
    for (int mf = 0; mf < 4; ++mf)
#pragma unroll
      for (int i = 0; i < 4; ++i) {
        const int rowg = brow + wm * 64 + mf * 16 + hq * 4 + i;
        const float inv = 1.0f / rowsum_in[rowg];
#pragma unroll
        for (int nf = 0; nf < 4; ++nf) {
          const int colg = bcol + wn * 64 + nf * 16 + lq;
          ((float*)Cout)[(size_t)rowg * N + colg] = acc[mf][nf][i] * inv + bias[colg];
        }
      }
  }
}

extern "C" void kernel_launch(void* const* d_in, const int* in_sizes, int n_in,
                              void* d_out, int out_size, void* d_ws, size_t ws_size,
                              hipStream_t stream) {
  const float* model = (const float*)d_in[0];
  const float* ctx   = (const float*)d_in[1];
  const float* Wq = (const float*)d_in[2]; const float* bq = (const float*)d_in[3];
  const float* Wk = (const float*)d_in[4]; const float* bk = (const float*)d_in[5];
  const float* Wv = (const float*)d_in[6]; const float* bv = (const float*)d_in[7];
  const float* Wo = (const float*)d_in[8]; const float* bo = (const float*)d_in[9];
  float* out = (float*)d_out;

  char* ws = (char*)d_ws;
  size_t off = 0;
  auto alloc = [&](size_t bytes) -> void* {
    void* p = ws + off;
    off += (bytes + 255) & ~(size_t)255;
    return p;
  };
  unsigned short* model_bf = (unsigned short*)alloc((size_t)MB_T * DD * 2);
  unsigned short* ctx_bf   = (unsigned short*)alloc((size_t)CC * DD * 2);
  unsigned short* Wq_bf = (unsigned short*)alloc((size_t)DD * AA * 2);   // natural [D][A]
  unsigned short* Wk_bf = (unsigned short*)alloc((size_t)DD * AA * 2);   // natural [D][A]
  unsigned short* Wv_bf = (unsigned short*)alloc((size_t)DD * AA * 2);   // natural [D][A]
  unsigned short* WoT   = (unsigned short*)alloc((size_t)AA * PP * 2);   // [P][A]
  unsigned short* WkqT_bf = (unsigned short*)alloc((size_t)DD * DD * 2); // [d'][d]
  unsigned short* WvoT_bf = (unsigned short*)alloc((size_t)PP * DD * 2); // [p][d]
  unsigned short* KqT_bf  = (unsigned short*)alloc((size_t)CC * DD * 2); // [C][D]
  unsigned short* W2T_bf  = (unsigned short*)alloc((size_t)PP * CC * 2); // [P][C]
  float* bkq  = (float*)alloc((size_t)DD * 4);
  float* bvo  = (float*)alloc((size_t)PP * 4);
  float* wkbq = (float*)alloc((size_t)DD * 4);
  float* bqk  = (float*)alloc((size_t)CC * 4);
  float* lsum = (float*)alloc((size_t)MB_T * 4);
  unsigned short* P_bf = (unsigned short*)alloc((size_t)MB_T * CC * 2);  // 128 MiB

  const float scale = 0.04419417382415922f;  // 1/sqrt(512)

  cast_bf16_kernel<<<2048, 256, 0, stream>>>(model, model_bf, MB_T * DD / 4);
  cast_bf16_kernel<<<1024, 256, 0, stream>>>(ctx, ctx_bf, CC * DD / 4);
  cast_bf16_kernel<<<256, 256, 0, stream>>>(Wq, Wq_bf, DD * AA / 4);
  cast_bf16_kernel<<<256, 256, 0, stream>>>(Wk, Wk_bf, DD * AA / 4);
  cast_bf16_kernel<<<256, 256, 0, stream>>>(Wv, Wv_bf, DD * AA / 4);
  transpose_cast_kernel<<<dim3(16, 16), 256, 0, stream>>>(Wo, WoT, AA, PP);

  // bias folds
  rowdot_kernel<<<DD / 4, 256, 0, stream>>>(Wq_bf, bk, bkq, scale);    // bkq[d'] = s*Wq[d']·bk
  rowdot_kernel<<<DD / 4, 256, 0, stream>>>(Wk_bf, bq, wkbq, scale);   // wkbq[d] = s*Wk[d]·bq
  rowdot_kernel<<<PP / 4, 256, 0, stream>>>(WoT, bv, bvo, 1.0f);       // bvo[p] = Wo[:,p]·bv
  rowdot_kernel<<<CC / 4, 256, 0, stream>>>(ctx_bf, wkbq, bqk, 1.0f);  // bqk[c] = ctx[c]·wkbq

  // WkqT[d'][d] = s * sum_a Wq[d'][a] Wk[d][a]
  gemm2p_kernel<0><<<dim3(4, 4), 256, 0, stream>>>(
      Wq_bf, Wk_bf, nullptr, WkqT_bf, DD, DD, AA, scale);
  // WvoT[p][d] = sum_a Wo[a][p] Wv[d][a]
  gemm2p_kernel<0><<<dim3(4, 4), 256, 0, stream>>>(
      WoT, Wv_bf, nullptr, WvoT_bf, PP, DD, AA, 1.0f);

  // KqT = ctx @ WkqT^T + bkq -> bf16 [4096][512]
  gemm2p_kernel<0><<<dim3(4, 32), 256, 0, stream>>>(
      ctx_bf, WkqT_bf, bkq, KqT_bf, CC, DD, DD, 1.0f);
  // W2T = (ctx @ WvoT^T + bvo)^T -> bf16 [512][4096]
  gemm2p_kernel<1><<<dim3(4, 32), 256, 0, stream>>>(
      ctx_bf, WvoT_bf, bvo, W2T_bf, CC, PP, DD, 1.0f);

  // P = exp(model @ KqT^T + bqk[col]) -> bf16 [16384][4096]; lsum = row sums
  hipMemsetAsync(lsum, 0, (size_t)MB_T * 4, stream);
  gemm_dp_kernel<3><<<dim3(32, 128), 256, 0, stream>>>(
      model_bf, KqT_bf, nullptr, bqk, nullptr, lsum, P_bf, MB_T, CC, DD);

  // out = P @ W2T^T / lsum + bo -> f32 [16384][512]
  gemm_dp_kernel<5><<<dim3(4, 128), 256, 0, stream>>>(
      P_bf, W2T_bf, bo, nullptr, lsum, nullptr, out, MB_T, PP, CC);
}

// Round 5
// 363.145 us; speedup vs baseline: 1.7321x; 1.1305x over previous
//
#include <hip/hip_runtime.h>

// Problem dims
#define MB_T 16384   // B*T
#define DD   512     // model hidden
#define CC   4096    // context entries
#define AA   512     // attn dim
#define PP   512     // out dim

typedef __attribute__((ext_vector_type(4))) float f32x4;
typedef __attribute__((ext_vector_type(8))) short short8;

#define MFMA16(a, b, c) __builtin_amdgcn_mfma_f32_16x16x32_bf16((a), (b), (c), 0, 0, 0)

__device__ __forceinline__ unsigned short f2bf(float f) {
  union { float f; unsigned int u; } cv; cv.f = f;
  unsigned int u = cv.u;
  return (unsigned short)((u + 0x7FFFu + ((u >> 16) & 1u)) >> 16);
}
__device__ __forceinline__ float bf2f(unsigned short u) {
  union { unsigned int i; float f; } c; c.i = (unsigned int)u << 16; return c.f;
}

// async global->LDS, 16B per lane; lds dest is wave-uniform base (+lane*16 by HW)
__device__ __forceinline__ void gload16(const unsigned short* g, unsigned short* l) {
  __builtin_amdgcn_global_load_lds(
      (const __attribute__((address_space(1))) unsigned int*)g,
      (__attribute__((address_space(3))) unsigned int*)l, 16, 0, 0);
}

// ---------------- cast fp32 -> bf16, x4 vectorized ----------------
__global__ void cast_bf16_kernel(const float* __restrict__ in,
                                 unsigned short* __restrict__ out, int n4) {
  int i = blockIdx.x * blockDim.x + threadIdx.x;
  int stride = gridDim.x * blockDim.x;
  for (; i < n4; i += stride) {
    float4 v = reinterpret_cast<const float4*>(in)[i];
    ushort4 o;
    o.x = f2bf(v.x); o.y = f2bf(v.y); o.z = f2bf(v.z); o.w = f2bf(v.w);
    reinterpret_cast<ushort4*>(out)[i] = o;
  }
}

// ---------------- W [rows][cols] f32 -> WT [cols][rows] bf16 ----------------
__global__ __launch_bounds__(256) void transpose_cast_kernel(
    const float* __restrict__ W, unsigned short* __restrict__ WT, int rows, int cols) {
  __shared__ float t_s[32][33];
  int bi = blockIdx.y * 32, bj = blockIdx.x * 32;
  int r = threadIdx.x >> 3, c4 = (threadIdx.x & 7) * 4;
  float4 v = *reinterpret_cast<const float4*>(W + (size_t)(bi + r) * cols + bj + c4);
  t_s[r][c4 + 0] = v.x; t_s[r][c4 + 1] = v.y;
  t_s[r][c4 + 2] = v.z; t_s[r][c4 + 3] = v.w;
  __syncthreads();
  ushort4 o;
  o.x = f2bf(t_s[c4 + 0][r]);
  o.y = f2bf(t_s[c4 + 1][r]);
  o.z = f2bf(t_s[c4 + 2][r]);
  o.w = f2bf(t_s[c4 + 3][r]);
  *reinterpret_cast<ushort4*>(WT + (size_t)(bj + r) * rows + bi + c4) = o;
}

// ---------------- out[r] = scale * dot(mat[r,0:512], vec) ----------------
__global__ __launch_bounds__(256) void rowdot_kernel(
    const unsigned short* __restrict__ mat, const float* __restrict__ vec,
    float* __restrict__ outv, float scale) {
  const int lane = threadIdx.x & 63, wid = threadIdx.x >> 6;
  const int row = blockIdx.x * 4 + wid;
  const unsigned short* kr = mat + (size_t)row * 512 + lane * 8;
  float s = 0.f;
  ushort4 a = *reinterpret_cast<const ushort4*>(kr);
  ushort4 b = *reinterpret_cast<const ushort4*>(kr + 4);
  const float* bqp = vec + lane * 8;
  s += bf2f(a.x) * bqp[0]; s += bf2f(a.y) * bqp[1];
  s += bf2f(a.z) * bqp[2]; s += bf2f(a.w) * bqp[3];
  s += bf2f(b.x) * bqp[4]; s += bf2f(b.y) * bqp[5];
  s += bf2f(b.z) * bqp[6]; s += bf2f(b.w) * bqp[7];
#pragma unroll
  for (int d = 1; d < 64; d <<= 1) s += __shfl_xor(s, d);
  if (lane == 0) outv[row] = s * scale;
}

// ---------------- lsum[m] = sum_j lsp[m*64+j] ----------------
__global__ __launch_bounds__(256) void reduce_lsum_kernel(
    const float* __restrict__ lsp, float* __restrict__ lsum) {
  int m = blockIdx.x * blockDim.x + threadIdx.x;
  const float4* p = reinterpret_cast<const float4*>(lsp + (size_t)m * 64);
  float s = 0.f;
#pragma unroll
  for (int j = 0; j < 16; ++j) { float4 v = p[j]; s += v.x + v.y + v.z + v.w; }
  lsum[m] = s;
}

// ---------------- 2-phase double-buffered GEMM, tile TM x 128, BK=32 ----------------
// A [M][K] bf16, BT [N][K] bf16.
// MODE 0: C bf16 [M][N] = (acc + bias[col]) * alpha       (TM=128; bias may be null)
// MODE 1: C bf16 transposed [N][M] = acc + bias[col]      (TM=128)
// MODE 3: C bf16 [M][N] = exp(acc + colbias[col]); per-wave partial row-sums
//         -> psum_out[row*64 + bx*2 + wn]; coalesced P store via LDS repack (TM=128)
// MODE 5: C f32 [M][N] = acc / rowsum_in[row] + bias[col] (TM=64)
template <int MODE, int TM>
__global__ __launch_bounds__(256, 4) void gemm2p_kernel(
    const unsigned short* __restrict__ A, const unsigned short* __restrict__ BT,
    const float* __restrict__ bias, const float* __restrict__ colbias,
    const float* __restrict__ rowsum_in, float* __restrict__ psum_out,
    void* __restrict__ Cout, int M, int N, int K, float alpha) {
  constexpr int MFR = TM / 32;       // m-frags per wave (4 or 2)
  constexpr int WROW = TM / 2;       // rows per wm-group
  constexpr int ASZ = TM * 32;       // A elems per buffer
  constexpr int BSZ = 128 * 32;      // B elems per buffer
  constexpr int STG = 2 * ASZ + 2 * BSZ;
  constexpr int TOT = (MODE == 3 && STG < 128 * 136) ? 128 * 136 : STG;
  __shared__ unsigned short lds[TOT];

  const int tid = threadIdx.x;
  const int lane = tid & 63, wid = tid >> 6;
  const int hq = lane >> 4, lq = lane & 15;
  const int wm = wid >> 1, wn = wid & 1;

  // XCD-chunked swizzle (nwg divisible by 8 for all launches here)
  const int gx = gridDim.x;
  const int nwg = gx * gridDim.y;
  const int orig = blockIdx.y * gx + blockIdx.x;
  const int swz = (orig & 7) * (nwg >> 3) + (orig >> 3);
  const int bx = swz % gx, by = swz / gx;
  const int brow = by * TM, bcol = bx * 128;

  const unsigned short* ap = A + (size_t)(brow + (tid >> 2)) * K + (tid & 3) * 8;
  const unsigned short* bp = BT + (size_t)(bcol + (tid >> 2)) * K + (tid & 3) * 8;
  const size_t row64 = (size_t)64 * K;

  const int nt = K >> 5;
  // prologue: stage tile 0 into buffer 0
#pragma unroll
  for (int j = 0; j < TM / 64; ++j)
    gload16(ap + j * row64, lds + wid * 512 + j * 2048);
  gload16(bp, lds + 2 * ASZ + wid * 512);
  gload16(bp + row64, lds + 2 * ASZ + wid * 512 + 2048);
  __syncthreads();

  f32x4 acc[MFR][4] = {};
  for (int t = 0; t < nt; ++t) {
    const int cur = t & 1;
    if (t + 1 < nt) {  // issue next-tile staging before compute
      const int k0 = (t + 1) * 32;
      unsigned short* an = lds + (cur ^ 1) * ASZ + wid * 512;
      unsigned short* bn = lds + 2 * ASZ + (cur ^ 1) * BSZ + wid * 512;
#pragma unroll
      for (int j = 0; j < TM / 64; ++j)
        gload16(ap + k0 + j * row64, an + j * 2048);
      gload16(bp + k0, bn);
      gload16(bp + k0 + row64, bn + 2048);
    }
    const unsigned short* as0 = lds + cur * ASZ;
    const unsigned short* bs0 = lds + 2 * ASZ + cur * BSZ;
    short8 af[MFR], bfv[4];
#pragma unroll
    for (int mf = 0; mf < MFR; ++mf)
      af[mf] = *reinterpret_cast<const short8*>(&as0[(wm * WROW + mf * 16 + lq) * 32 + hq * 8]);
#pragma unroll
    for (int nf = 0; nf < 4; ++nf)
      bfv[nf] = *reinterpret_cast<const short8*>(&bs0[(wn * 64 + nf * 16 + lq) * 32 + hq * 8]);
#pragma unroll
    for (int mf = 0; mf < MFR; ++mf)
#pragma unroll
      for (int nf = 0; nf < 4; ++nf)
        acc[mf][nf] = MFMA16(af[mf], bfv[nf], acc[mf][nf]);
    if (t + 1 < nt) __syncthreads();
  }

  if (MODE == 3) {
    float cb[4];
#pragma unroll
    for (int nf = 0; nf < 4; ++nf) cb[nf] = colbias[bcol + wn * 64 + nf * 16 + lq];
    __syncthreads();  // all waves done reading staging LDS; reuse as p_s
#pragma unroll
    for (int mf = 0; mf < MFR; ++mf)
#pragma unroll
      for (int i = 0; i < 4; ++i) {
        const int rowl = wm * WROW + mf * 16 + hq * 4 + i;
        float s = 0.f;
#pragma unroll
        for (int nf = 0; nf < 4; ++nf) {
          float p = __expf(acc[mf][nf][i] + cb[nf]);
          s += p;
          lds[rowl * 136 + wn * 64 + nf * 16 + lq] = f2bf(p);
        }
        s += __shfl_xor(s, 1);
        s += __shfl_xor(s, 2);
        s += __shfl_xor(s, 4);
        s += __shfl_xor(s, 8);
        if (lq == 0) psum_out[(size_t)(brow + rowl) * 64 + bx * 2 + wn] = s;
      }
    __syncthreads();
    // coalesced packed store: 2048 chunks of 16B
#pragma unroll
    for (int j = 0; j < 8; ++j) {
      const int chunk = j * 256 + tid;
      const int row = chunk >> 4, c = chunk & 15;
      short8 v = *reinterpret_cast<const short8*>(&lds[row * 136 + c * 8]);
      *reinterpret_cast<short8*>((unsigned short*)Cout + (size_t)(brow + row) * N + bcol + c * 8) = v;
    }
  } else if (MODE == 5) {
#pragma unroll
    for (int mf = 0; mf < MFR; ++mf)
#pragma unroll
      for (int i = 0; i < 4; ++i) {
        const int rowg = brow + wm * WROW + mf * 16 + hq * 4 + i;
        const float inv = 1.0f / rowsum_in[rowg];
#pragma unroll
        for (int nf = 0; nf < 4; ++nf) {
          const int colg = bcol + wn * 64 + nf * 16 + lq;
          ((float*)Cout)[(size_t)rowg * N + colg] = acc[mf][nf][i] * inv + bias[colg];
        }
      }
  } else if (MODE == 1) {
#pragma unroll
    for (int nf = 0; nf < 4; ++nf) {
      const int colg = bcol + wn * 64 + nf * 16 + lq;
      const float bv = bias ? bias[colg] : 0.f;
#pragma unroll
      for (int mf = 0; mf < MFR; ++mf) {
        const int rowg0 = brow + wm * WROW + mf * 16 + hq * 4;
        ushort4 pk;
        pk.x = f2bf(acc[mf][nf][0] + bv);
        pk.y = f2bf(acc[mf][nf][1] + bv);
        pk.z = f2bf(acc[mf][nf][2] + bv);
        pk.w = f2bf(acc[mf][nf][3] + bv);
        *reinterpret_cast<ushort4*>((unsigned short*)Cout + (size_t)colg * M + rowg0) = pk;
      }
    }
  } else {
#pragma unroll
    for (int nf = 0; nf < 4; ++nf) {
      const int colg = bcol + wn * 64 + nf * 16 + lq;
      const float bv = bias ? bias[colg] : 0.f;
#pragma unroll
      for (int mf = 0; mf < MFR; ++mf) {
        const int rowg0 = brow + wm * WROW + mf * 16 + hq * 4;
#pragma unroll
        for (int i = 0; i < 4; ++i)
          ((unsigned short*)Cout)[(size_t)(rowg0 + i) * N + colg] =
              f2bf((acc[mf][nf][i] + bv) * alpha);
      }
    }
  }
}

extern "C" void kernel_launch(void* const* d_in, const int* in_sizes, int n_in,
                              void* d_out, int out_size, void* d_ws, size_t ws_size,
                              hipStream_t stream) {
  const float* model = (const float*)d_in[0];
  const float* ctx   = (const float*)d_in[1];
  const float* Wq = (const float*)d_in[2]; const float* bq = (const float*)d_in[3];
  const float* Wk = (const float*)d_in[4]; const float* bk = (const float*)d_in[5];
  const float* Wv = (const float*)d_in[6]; const float* bv = (const float*)d_in[7];
  const float* Wo = (const float*)d_in[8]; const float* bo = (const float*)d_in[9];
  float* out = (float*)d_out;

  char* ws = (char*)d_ws;
  size_t off = 0;
  auto alloc = [&](size_t bytes) -> void* {
    void* p = ws + off;
    off += (bytes + 255) & ~(size_t)255;
    return p;
  };
  unsigned short* model_bf = (unsigned short*)alloc((size_t)MB_T * DD * 2);
  unsigned short* ctx_bf   = (unsigned short*)alloc((size_t)CC * DD * 2);
  unsigned short* Wq_bf = (unsigned short*)alloc((size_t)DD * AA * 2);   // natural [D][A]
  unsigned short* Wk_bf = (unsigned short*)alloc((size_t)DD * AA * 2);   // natural [D][A]
  unsigned short* Wv_bf = (unsigned short*)alloc((size_t)DD * AA * 2);   // natural [D][A]
  unsigned short* WoT   = (unsigned short*)alloc((size_t)AA * PP * 2);   // [P][A]
  unsigned short* WkqT_bf = (unsigned short*)alloc((size_t)DD * DD * 2); // [d'][d]
  unsigned short* WvoT_bf = (unsigned short*)alloc((size_t)PP * DD * 2); // [p][d]
  unsigned short* KqT_bf  = (unsigned short*)alloc((size_t)CC * DD * 2); // [C][D]
  unsigned short* W2T_bf  = (unsigned short*)alloc((size_t)PP * CC * 2); // [P][C]
  float* bkq  = (float*)alloc((size_t)DD * 4);
  float* bvo  = (float*)alloc((size_t)PP * 4);
  float* wkbq = (float*)alloc((size_t)DD * 4);
  float* bqk  = (float*)alloc((size_t)CC * 4);
  float* lsp  = (float*)alloc((size_t)MB_T * 64 * 4);  // per-(row, colblock*2+wn) partials
  float* lsum = (float*)alloc((size_t)MB_T * 4);
  unsigned short* P_bf = (unsigned short*)alloc((size_t)MB_T * CC * 2);  // 128 MiB

  const float scale = 0.04419417382415922f;  // 1/sqrt(512)

  cast_bf16_kernel<<<2048, 256, 0, stream>>>(model, model_bf, MB_T * DD / 4);
  cast_bf16_kernel<<<1024, 256, 0, stream>>>(ctx, ctx_bf, CC * DD / 4);
  cast_bf16_kernel<<<256, 256, 0, stream>>>(Wq, Wq_bf, DD * AA / 4);
  cast_bf16_kernel<<<256, 256, 0, stream>>>(Wk, Wk_bf, DD * AA / 4);
  cast_bf16_kernel<<<256, 256, 0, stream>>>(Wv, Wv_bf, DD * AA / 4);
  transpose_cast_kernel<<<dim3(16, 16), 256, 0, stream>>>(Wo, WoT, AA, PP);

  // bias folds
  rowdot_kernel<<<DD / 4, 256, 0, stream>>>(Wq_bf, bk, bkq, scale);    // bkq[d'] = s*Wq[d']·bk
  rowdot_kernel<<<DD / 4, 256, 0, stream>>>(Wk_bf, bq, wkbq, scale);   // wkbq[d] = s*Wk[d]·bq
  rowdot_kernel<<<PP / 4, 256, 0, stream>>>(WoT, bv, bvo, 1.0f);       // bvo[p] = Wo[:,p]·bv
  rowdot_kernel<<<CC / 4, 256, 0, stream>>>(ctx_bf, wkbq, bqk, 1.0f);  // bqk[c] = ctx[c]·wkbq

  // WkqT[d'][d] = s * sum_a Wq[d'][a] Wk[d][a]
  gemm2p_kernel<0, 128><<<dim3(4, 4), 256, 0, stream>>>(
      Wq_bf, Wk_bf, nullptr, nullptr, nullptr, nullptr, WkqT_bf, DD, DD, AA, scale);
  // WvoT[p][d] = sum_a Wo[a][p] Wv[d][a]
  gemm2p_kernel<0, 128><<<dim3(4, 4), 256, 0, stream>>>(
      WoT, Wv_bf, nullptr, nullptr, nullptr, nullptr, WvoT_bf, PP, DD, AA, 1.0f);

  // KqT = ctx @ WkqT^T + bkq -> bf16 [4096][512]
  gemm2p_kernel<0, 128><<<dim3(4, 32), 256, 0, stream>>>(
      ctx_bf, WkqT_bf, bkq, nullptr, nullptr, nullptr, KqT_bf, CC, DD, DD, 1.0f);
  // W2T = (ctx @ WvoT^T + bvo)^T -> bf16 [512][4096]
  gemm2p_kernel<1, 128><<<dim3(4, 32), 256, 0, stream>>>(
      ctx_bf, WvoT_bf, bvo, nullptr, nullptr, nullptr, W2T_bf, CC, PP, DD, 1.0f);

  // P = exp(model @ KqT^T + bqk[col]) -> bf16 [16384][4096]; partial row sums -> lsp
  gemm2p_kernel<3, 128><<<dim3(32, 128), 256, 0, stream>>>(
      model_bf, KqT_bf, nullptr, bqk, nullptr, lsp, P_bf, MB_T, CC, DD, 1.0f);

  // lsum = reduce(lsp)
  reduce_lsum_kernel<<<MB_T / 256, 256, 0, stream>>>(lsp, lsum);

  // out = P @ W2T^T / lsum + bo -> f32 [16384][512]  (64-row tiles, 1024 blocks)
  gemm2p_kernel<5, 64><<<dim3(4, 256), 256, 0, stream>>>(
      P_bf, W2T_bf, bo, nullptr, lsum, nullptr, out, MB_T, PP, CC, 1.0f);
}